// Round 1
// baseline (409.534 us; speedup 1.0000x reference)
//
#include <hip/hip_runtime.h>

// ---------------------------------------------------------------------------
// GCN variational encoder (mu, logvar) on MI355X.
// Restructure: out = Â (X W) == (Â X) W  since everything is linear.
//   Â = D^-1/2 (A + I) D^-1/2
//   norm factorizes: agg[d] = dinv[d] * sum_{s->d} dinv[s]*x[s]  (+ self loop)
// So: xs = x * dinv[row]; agg = scatter_add(xs) + xs (self loop);
//     h = agg * dinv[row]; mu = h@Wmu + bmu; logvar = h@Wlv + blv.
// One scatter pass (64-wide) instead of two.
// ---------------------------------------------------------------------------

__global__ void k_zero_deg(int* __restrict__ deg, int n) {
    int i = blockIdx.x * blockDim.x + threadIdx.x;
    if (i < n) deg[i] = 0;
}

__global__ void k_count_deg(const int* __restrict__ dst, int e, int* __restrict__ deg) {
    int i = blockIdx.x * blockDim.x + threadIdx.x;
    if (i < e) atomicAdd(&deg[dst[i]], 1);
}

__global__ void k_dinv(const int* __restrict__ deg, float* __restrict__ dinv, int n) {
    int i = blockIdx.x * blockDim.x + threadIdx.x;
    if (i < n) dinv[i] = rsqrtf((float)(deg[i] + 1));  // +1 = self loop
}

// xs = x * dinv[row]  (float4-vectorized, 16 float4 per row)
// agg (first half of d_out) initialized to xs  -> self-loop term included.
__global__ void k_scale_init(const float4* __restrict__ x4, const float* __restrict__ dinv,
                             float4* __restrict__ xs4, float4* __restrict__ agg4, int n16) {
    int i = blockIdx.x * blockDim.x + threadIdx.x;
    if (i < n16) {
        float s = dinv[i >> 4];
        float4 v = x4[i];
        v.x *= s; v.y *= s; v.z *= s; v.w *= s;
        xs4[i] = v;
        agg4[i] = v;
    }
}

// One lane per (edge, col): agg[dst][j] += xs[src][j].
// 64 lanes of a wave share one edge -> src/dst loads broadcast, the gather
// xs[src*64 + j] is a contiguous 256B read, atomics land on one agg row.
__global__ void k_scatter(const int* __restrict__ src, const int* __restrict__ dst,
                          const float* __restrict__ xs, float* __restrict__ agg, int total) {
    int g = blockIdx.x * blockDim.x + threadIdx.x;
    if (g >= total) return;
    int e = g >> 6;
    int j = g & 63;
    int s = src[e];
    int d = dst[e];
    atomicAdd(agg + (((size_t)d) << 6) + j, xs[(((size_t)s) << 6) + j]);
}

// Fused epilogue: per 64-row tile, h = agg*dinv staged in LDS, both 64x64
// GEMMs computed sharing the h reads. Writes are row-local (in-place safe:
// mu aliases agg for this block's own rows, read happens before the write).
__global__ __launch_bounds__(256) void k_gemm2(
        const float* __restrict__ agg, const float* __restrict__ dinv,
        const float* __restrict__ Wmu, const float* __restrict__ bmu,
        const float* __restrict__ Wlv, const float* __restrict__ blv,
        float* __restrict__ mu, float* __restrict__ lv, int n) {
    __shared__ float wmu_s[64 * 64];
    __shared__ float wlv_s[64 * 64];
    __shared__ float h_s[64 * 64];

    const int tid  = threadIdx.x;
    const int row0 = blockIdx.x * 64;

    // Stage both weight matrices (4096 floats each = 1024 float4).
    for (int t = tid; t < 1024; t += 256) {
        ((float4*)wmu_s)[t] = ((const float4*)Wmu)[t];
        ((float4*)wlv_s)[t] = ((const float4*)Wlv)[t];
    }
    // Stage h = agg * dinv for this 64-row tile (1024 float4 units).
    for (int t = tid; t < 1024; t += 256) {
        int r  = t >> 4;          // 0..63
        int c4 = t & 15;          // 0..15
        int row = row0 + r;
        if (row < n) {
            float4 v = ((const float4*)agg)[(size_t)row * 16 + c4];
            float s = dinv[row];
            v.x *= s; v.y *= s; v.z *= s; v.w *= s;
            ((float4*)h_s)[(size_t)r * 16 + c4] = v;
        }
    }
    __syncthreads();

    const int j  = tid & 63;
    const int rg = tid >> 6;          // 0..3, each handles 16 rows
    const float bj_mu = bmu[j];
    const float bj_lv = blv[j];

    for (int it = 0; it < 16; ++it) {
        int r   = rg * 16 + it;
        int row = row0 + r;
        if (row >= n) continue;
        float amu = bj_mu;
        float alv = bj_lv;
        #pragma unroll
        for (int k = 0; k < 64; ++k) {
            float hv = h_s[r * 64 + k];          // broadcast across the 64-lane group
            amu = fmaf(hv, wmu_s[k * 64 + j], amu);  // consecutive j -> conflict-free
            alv = fmaf(hv, wlv_s[k * 64 + j], alv);
        }
        mu[(size_t)row * 64 + j] = amu;
        lv[(size_t)row * 64 + j] = alv;
    }
}

extern "C" void kernel_launch(void* const* d_in, const int* in_sizes, int n_in,
                              void* d_out, int out_size, void* d_ws, size_t ws_size,
                              hipStream_t stream) {
    const float* x   = (const float*)d_in[0];
    const int* eidx  = (const int*)d_in[1];
    const float* Wmu = (const float*)d_in[2];
    const float* bmu = (const float*)d_in[3];
    const float* Wlv = (const float*)d_in[4];
    const float* blv = (const float*)d_in[5];

    const int N = in_sizes[0] / 64;
    const int E = in_sizes[1] / 2;
    const int* src = eidx;        // edge_index[0]
    const int* dst = eidx + E;    // edge_index[1]

    // Workspace layout (256B-aligned): deg[N] int, dinv[N] f32, xs[N*64] f32.
    char* ws = (char*)d_ws;
    size_t off = 0;
    int* deg = (int*)(ws + off);       off += ((size_t)N * 4 + 255) & ~(size_t)255;
    float* dinv = (float*)(ws + off);  off += ((size_t)N * 4 + 255) & ~(size_t)255;
    float* xs = (float*)(ws + off);    off += ((size_t)N * 64 * 4 + 255) & ~(size_t)255;

    float* mu  = (float*)d_out;            // first half; doubles as agg scratch
    float* lv  = mu + (size_t)N * 64;      // second half
    float* agg = mu;

    const int B = 256;
    k_zero_deg<<<(N + B - 1) / B, B, 0, stream>>>(deg, N);
    k_count_deg<<<(E + B - 1) / B, B, 0, stream>>>(dst, E, deg);
    k_dinv<<<(N + B - 1) / B, B, 0, stream>>>(deg, dinv, N);

    const int n16 = N * 16;
    k_scale_init<<<(n16 + B - 1) / B, B, 0, stream>>>(
        (const float4*)x, dinv, (float4*)xs, (float4*)agg, n16);

    const int total = E * 64;  // 76.8M, fits int32
    k_scatter<<<(total + B - 1) / B, B, 0, stream>>>(src, dst, xs, agg, total);

    k_gemm2<<<(N + 63) / 64, B, 0, stream>>>(agg, dinv, Wmu, bmu, Wlv, blv, mu, lv, N);
}

// Round 2
// 289.152 us; speedup vs baseline: 1.4163x; 1.4163x over previous
//
#include <hip/hip_runtime.h>

// ---------------------------------------------------------------------------
// GCN variational encoder (mu, logvar) on MI355X — round 2.
//
//   out = Â (X W) == (Â X) W,  Â = D^-1/2 (A+I) D^-1/2
//   h[n] = dinv[n] * ( dinv[n]*x[n] + sum_{s->n} dinv[s]*x[s] )
//   mu = h@Wmu + bmu ; logvar = h@Wlv + blv
//
// Round-1 scatter used 76.8M global f32 atomics -> 307MB fabric writes, 261us.
// Round 2: counting-sort edges by dst into CSR, then gather-aggregate with one
// wave per node, accumulating in registers. Zero atomics in the hot loop.
// ---------------------------------------------------------------------------

__global__ void k_zero(int* __restrict__ p, int n) {
    int i = blockIdx.x * blockDim.x + threadIdx.x;
    if (i < n) p[i] = 0;
}

__global__ void k_deg(const int* __restrict__ dst, int e, int* __restrict__ deg) {
    int i = blockIdx.x * blockDim.x + threadIdx.x;
    if (i < e) atomicAdd(&deg[dst[i]], 1);
}

__global__ void k_dinv(const int* __restrict__ deg, float* __restrict__ dinv, int n) {
    int i = blockIdx.x * blockDim.x + threadIdx.x;
    if (i < n) dinv[i] = rsqrtf((float)(deg[i] + 1));  // +1 = self loop
}

// --- 3-kernel exclusive scan of deg[] -> start[] (segment offsets) ---------
__global__ void k_scan_block(const int* __restrict__ deg, int* __restrict__ start,
                             int* __restrict__ partial, int n) {
    __shared__ int sm[256];
    const int tid = threadIdx.x;
    const int i = blockIdx.x * 256 + tid;
    int v = (i < n) ? deg[i] : 0;
    sm[tid] = v;
    __syncthreads();
    for (int off = 1; off < 256; off <<= 1) {
        int t = (tid >= off) ? sm[tid - off] : 0;
        __syncthreads();
        sm[tid] += t;
        __syncthreads();
    }
    if (i < n) start[i] = sm[tid] - v;               // exclusive within block
    if (tid == 255) partial[blockIdx.x] = sm[255];   // block total
}

// single block; nb must be <= 512 (here nb = ceil(100000/256) = 391)
__global__ void k_scan_partial(int* __restrict__ partial, int nb) {
    __shared__ int sm[512];
    const int tid = threadIdx.x;
    int v = (tid < nb) ? partial[tid] : 0;
    sm[tid] = v;
    __syncthreads();
    for (int off = 1; off < 512; off <<= 1) {
        int t = (tid >= off) ? sm[tid - off] : 0;
        __syncthreads();
        sm[tid] += t;
        __syncthreads();
    }
    if (tid < nb) partial[tid] = sm[tid] - v;        // exclusive
}

__global__ void k_scan_add(int* __restrict__ start, int* __restrict__ cursor,
                           const int* __restrict__ partial, int n) {
    int i = blockIdx.x * blockDim.x + threadIdx.x;
    if (i < n) {
        int s = start[i] + partial[i >> 8];
        start[i] = s;
        cursor[i] = s;
    }
}

// scatter edges into CSR order (order within a segment is arbitrary; the FP
// sum in k_agg is reassociated anyway, well within the absmax threshold)
__global__ void k_sort(const int* __restrict__ src, const int* __restrict__ dst, int e,
                       int* __restrict__ cursor, int* __restrict__ srcSorted) {
    int i = blockIdx.x * blockDim.x + threadIdx.x;
    if (i < e) {
        int d = dst[i];
        int p = atomicAdd(&cursor[d], 1);
        srcSorted[p] = src[i];
    }
}

// --- gather aggregation: one 64-lane wave per node, register accumulator ---
__global__ __launch_bounds__(256) void k_agg(
        const float* __restrict__ x, const float* __restrict__ dinv,
        const int* __restrict__ start, const int* __restrict__ deg,
        const int* __restrict__ srcSorted, float* __restrict__ h, int n) {
    const int j = threadIdx.x & 63;
    const int node = blockIdx.x * 4 + (threadIdx.x >> 6);
    if (node >= n) return;
    const float dn = dinv[node];
    float acc = dn * x[((size_t)node << 6) + j];     // self loop
    const int s0 = start[node];
    const int d = deg[node];
    int k = 0;
    for (; k + 4 <= d; k += 4) {                     // 4-wide ILP on the gather
        int a = srcSorted[s0 + k];
        int b = srcSorted[s0 + k + 1];
        int c = srcSorted[s0 + k + 2];
        int e4 = srcSorted[s0 + k + 3];
        float fa = dinv[a] * x[((size_t)a << 6) + j];
        float fb = dinv[b] * x[((size_t)b << 6) + j];
        float fc = dinv[c] * x[((size_t)c << 6) + j];
        float fd = dinv[e4] * x[((size_t)e4 << 6) + j];
        acc += (fa + fb) + (fc + fd);
    }
    for (; k < d; ++k) {
        int s = srcSorted[s0 + k];
        acc += dinv[s] * x[((size_t)s << 6) + j];
    }
    h[((size_t)node << 6) + j] = dn * acc;
}

// --- fused dual GEMM: mu = h@Wmu+bmu, lv = h@Wlv+blv ------------------------
// W columns live in registers (64+64 VGPR); h tile staged in LDS, read as
// float4 broadcasts. In-place safe: h aliases mu, each block stages its own
// 64 rows before overwriting them.
__global__ __launch_bounds__(256) void k_gemm2(
        const float* __restrict__ h,
        const float* __restrict__ Wmu, const float* __restrict__ bmu,
        const float* __restrict__ Wlv, const float* __restrict__ blv,
        float* __restrict__ mu, float* __restrict__ lv, int n) {
    __shared__ float4 h4[64 * 16];
    const int tid = threadIdx.x;
    const int row0 = blockIdx.x * 64;

    for (int t = tid; t < 1024; t += 256) {
        int r = t >> 4, c = t & 15;
        int row = row0 + r;
        h4[t] = (row < n) ? ((const float4*)h)[(size_t)row * 16 + c]
                          : make_float4(0.f, 0.f, 0.f, 0.f);
    }

    const int j = tid & 63;
    const int rg = tid >> 6;
    float wmu_r[64], wlv_r[64];
    #pragma unroll
    for (int k = 0; k < 64; ++k) {                   // coalesced 256B per k
        wmu_r[k] = Wmu[k * 64 + j];
        wlv_r[k] = Wlv[k * 64 + j];
    }
    const float bm = bmu[j];
    const float bl = blv[j];
    __syncthreads();

    for (int it = 0; it < 16; ++it) {
        int r = rg * 16 + it;
        int row = row0 + r;
        if (row >= n) break;
        float am = bm, al = bl;
        #pragma unroll
        for (int kq = 0; kq < 16; ++kq) {
            float4 hv = h4[r * 16 + kq];             // wave-broadcast LDS read
            am = fmaf(hv.x, wmu_r[4 * kq],     am);
            am = fmaf(hv.y, wmu_r[4 * kq + 1], am);
            am = fmaf(hv.z, wmu_r[4 * kq + 2], am);
            am = fmaf(hv.w, wmu_r[4 * kq + 3], am);
            al = fmaf(hv.x, wlv_r[4 * kq],     al);
            al = fmaf(hv.y, wlv_r[4 * kq + 1], al);
            al = fmaf(hv.z, wlv_r[4 * kq + 2], al);
            al = fmaf(hv.w, wlv_r[4 * kq + 3], al);
        }
        mu[(size_t)row * 64 + j] = am;
        lv[(size_t)row * 64 + j] = al;
    }
}

extern "C" void kernel_launch(void* const* d_in, const int* in_sizes, int n_in,
                              void* d_out, int out_size, void* d_ws, size_t ws_size,
                              hipStream_t stream) {
    const float* x   = (const float*)d_in[0];
    const int* eidx  = (const int*)d_in[1];
    const float* Wmu = (const float*)d_in[2];
    const float* bmu = (const float*)d_in[3];
    const float* Wlv = (const float*)d_in[4];
    const float* blv = (const float*)d_in[5];

    const int N = in_sizes[0] / 64;
    const int E = in_sizes[1] / 2;
    const int* src = eidx;        // edge_index[0]
    const int* dst = eidx + E;    // edge_index[1]

    // ws: deg[N] dinv[N] start[N] cursor[N] partial[512] srcSorted[E]  (~6.4MB)
    char* ws = (char*)d_ws;
    size_t off = 0;
    int*   deg    = (int*)(ws + off);   off += ((size_t)N * 4 + 255) & ~(size_t)255;
    float* dinv   = (float*)(ws + off); off += ((size_t)N * 4 + 255) & ~(size_t)255;
    int*   start  = (int*)(ws + off);   off += ((size_t)N * 4 + 255) & ~(size_t)255;
    int*   cursor = (int*)(ws + off);   off += ((size_t)N * 4 + 255) & ~(size_t)255;
    int*   partial= (int*)(ws + off);   off += 512 * 4;
    int*   srcS   = (int*)(ws + off);   off += ((size_t)E * 4 + 255) & ~(size_t)255;

    float* mu = (float*)d_out;             // h aliases mu (in-place GEMM)
    float* lv = mu + (size_t)N * 64;
    float* h  = mu;

    const int B = 256;
    const int nb = (N + 255) / 256;        // scan blocks (391 <= 512)

    k_zero<<<(N + B - 1) / B, B, 0, stream>>>(deg, N);
    k_deg<<<(E + B - 1) / B, B, 0, stream>>>(dst, E, deg);
    k_dinv<<<(N + B - 1) / B, B, 0, stream>>>(deg, dinv, N);

    k_scan_block<<<nb, 256, 0, stream>>>(deg, start, partial, N);
    k_scan_partial<<<1, 512, 0, stream>>>(partial, nb);
    k_scan_add<<<(N + B - 1) / B, B, 0, stream>>>(start, cursor, partial, N);

    k_sort<<<(E + B - 1) / B, B, 0, stream>>>(src, dst, E, cursor, srcS);

    k_agg<<<(N + 3) / 4, 256, 0, stream>>>(x, dinv, start, deg, srcS, h, N);

    k_gemm2<<<(N + 63) / 64, 256, 0, stream>>>(h, Wmu, bmu, Wlv, blv, mu, lv, N);
}